// Round 3
// 203.918 us; speedup vs baseline: 1.4460x; 1.4460x over previous
//
#include <hip/hip_runtime.h>
#include <hip/hip_bf16.h>

// Problem constants
#define B_  16
#define N_  512
#define M_  16
#define H_  8
#define D_  128
#define BN_ 8192   // B_*N_
#define NB  16     // nodes per block in main kernel

typedef __attribute__((ext_vector_type(4))) float          f32x4;
typedef __attribute__((ext_vector_type(8))) short          s16x8;  // 8 bf16 (guide-blessed)
typedef __attribute__((ext_vector_type(8))) unsigned short u16x8;
typedef __attribute__((ext_vector_type(8))) _Float16       f16x8;

static __device__ __forceinline__ float bf2f(__hip_bfloat16 x) { return __bfloat162float(x); }
static __device__ __forceinline__ unsigned short f2bu(float x) {
    __hip_bfloat16 b = __float2bfloat16(x);
    return *reinterpret_cast<unsigned short*>(&b);
}
static __device__ __forceinline__ float bu2f(unsigned short u) {
    return __uint_as_float(((unsigned int)u) << 16);
}

// Load/store policy: interpret float tensors as f32 or bf16.
template <bool F32>
struct Pol {
    static __device__ __forceinline__ float ld(const void* p, int i) {
        if constexpr (F32) return ((const float*)p)[i];
        else               return bf2f(((const __hip_bfloat16*)p)[i]);
    }
    static __device__ __forceinline__ float4 ld4(const void* p, int i) {  // i%4==0
        if constexpr (F32) return *(const float4*)((const float*)p + i);
        else {
            const ushort4 u = *(const ushort4*)((const unsigned short*)p + i);
            return make_float4(bu2f(u.x), bu2f(u.y), bu2f(u.z), bu2f(u.w));
        }
    }
    static __device__ __forceinline__ void ld8(const void* p, long i, float* v) {  // i%8==0
        if constexpr (F32) {
            const float4 a = *(const float4*)((const float*)p + i);
            const float4 b = *(const float4*)((const float*)p + i + 4);
            v[0]=a.x; v[1]=a.y; v[2]=a.z; v[3]=a.w;
            v[4]=b.x; v[5]=b.y; v[6]=b.z; v[7]=b.w;
        } else {
            const u16x8 u = *(const u16x8*)((const unsigned short*)p + i);
            #pragma unroll
            for (int j = 0; j < 8; ++j) v[j] = bu2f(u[j]);
        }
    }
    static __device__ __forceinline__ void st8(void* p, long i, const float* v) {  // i%8==0
        if constexpr (F32) {
            *(float4*)((float*)p + i)     = make_float4(v[0], v[1], v[2], v[3]);
            *(float4*)((float*)p + i + 4) = make_float4(v[4], v[5], v[6], v[7]);
        } else {
            u16x8 u;
            #pragma unroll
            for (int j = 0; j < 8; ++j) u[j] = f2bu(v[j]);
            *(u16x8*)((unsigned short*)p + i) = u;
        }
    }
};

// Dtype probe (verbatim): f32 buffers read as bf16 at even index give
// random-exponent garbage; genuine bf16 stays small.
static __device__ __forceinline__ bool probe_is_f32(const void* h) {
    bool is_f32 = false;
    const __hip_bfloat16* hb = (const __hip_bfloat16*)h;
    for (int i = 0; i < 128; ++i) {
        const float v = bf2f(hb[2 * i]);
        if (!(fabsf(v) < 1e4f)) is_f32 = true;
    }
    return is_f32;
}

// ---------------------------------------------------------------------------
// K0 (prep, grid 520):
//   blk <  512 : WeffT[o][hd] = bf16( sum_e W[hd][e] * Wo[(h*128+e)][o] )
//                (2 hd rows per block; hd = h*128+d)
//   blk >= 512 : wsrc/wdst[h][d] = sum_e W[h][d][e] * a_{src,dst}[h][e]  (f32)
// ---------------------------------------------------------------------------
template <bool F32>
static __device__ __forceinline__ void k0_body(
        const void* __restrict__ W,  const void* __restrict__ Wo,
        const void* __restrict__ a_src, const void* __restrict__ a_dst,
        float* __restrict__ wsrc, float* __restrict__ wdst,
        unsigned short* __restrict__ WeffT, float* wrow /* shared [2*128] */) {
    using P = Pol<F32>;
    const int blk = blockIdx.x;
    const int t   = threadIdx.x;
    if (blk < 512) {
        const int half = t >> 7, o = t & 127;
        const int hd = blk * 2 + half;               // hd = h*128 + d
        wrow[half * 128 + o] = P::ld(W, hd * 128 + o);
        __syncthreads();
        const int hh = hd >> 7;
        float acc = 0.f;
        #pragma unroll 8
        for (int e = 0; e < 128; ++e)
            acc += wrow[half * 128 + e] * P::ld(Wo, (hh * 128 + e) * 128 + o);
        WeffT[(size_t)o * 1024 + hd] = f2bu(acc);
    } else {
        const int hh = blk - 512;
        const int which = t >> 7, d = t & 127;
        const void* av = which ? a_dst : a_src;
        const int wbase = hh * (D_ * D_) + d * 128;
        float acc = 0.f;
        #pragma unroll 8
        for (int e = 0; e < 128; e += 4) {
            const float4 wv = P::ld4(W, wbase + e);
            const float4 aa = P::ld4(av, hh * 128 + e);
            acc += wv.x * aa.x + wv.y * aa.y + wv.z * aa.z + wv.w * aa.w;
        }
        (which ? wdst : wsrc)[hh * 128 + d] = acc;
    }
}

__global__ __launch_bounds__(256) void k0(
        const void* W, const void* Wo, const void* a_src, const void* a_dst,
        const void* h, float* wsrc, float* wdst, unsigned short* WeffT) {
    __shared__ float wrow[2 * 128];
    if (probe_is_f32(h)) k0_body<true >(W, Wo, a_src, a_dst, wsrc, wdst, WeffT, wrow);
    else                 k0_body<false>(W, Wo, a_src, a_dst, wsrc, wdst, WeffT, wrow);
}

// ---------------------------------------------------------------------------
// K1: scores.  16 nodes/block; stage h-rows + wsrc/wdst in LDS (padded rows),
// then one f32 dot per (node, head, src/dst) thread.  Outputs f16.
// grid 512 x 256.
// ---------------------------------------------------------------------------
template <bool F32>
static __device__ __forceinline__ void k1_body(
        const void* __restrict__ h, const float* __restrict__ wsrc,
        const float* __restrict__ wdst, _Float16* __restrict__ ssrc_h,
        _Float16* __restrict__ sdst_h, float* hls /*[16*132]*/, float* wls /*[16*132]*/) {
    using P = Pol<F32>;
    const int t   = threadIdx.x;
    const int bn0 = blockIdx.x * 16;
    {
        const int r = t >> 4, c0 = (t & 15) * 8;
        float v[8];
        P::ld8(h, (long)(bn0 + r) * 128 + c0, v);
        #pragma unroll
        for (int j = 0; j < 8; ++j) hls[r * 132 + c0 + j] = v[j];
        const int c = t >> 4;                         // c = which*8 + head
        const float* wp = (c >> 3) ? wdst : wsrc;
        const int woff = (c & 7) * 128 + c0;
        #pragma unroll
        for (int j = 0; j < 8; ++j) wls[c * 132 + c0 + j] = wp[woff + j];
    }
    __syncthreads();
    const int n = t >> 4, c = t & 15;
    float acc = 0.f;
    #pragma unroll
    for (int e = 0; e < 128; e += 4) {
        const float4 hv = *(const float4*)(hls + n * 132 + e);
        const float4 wv = *(const float4*)(wls + c * 132 + e);
        acc += hv.x * wv.x + hv.y * wv.y + hv.z * wv.z + hv.w * wv.w;
    }
    const int node = bn0 + n;
    if (c < 8) ssrc_h[node * 8 + c]       = (_Float16)acc;
    else       sdst_h[node * 8 + (c - 8)] = (_Float16)acc;
}

__global__ __launch_bounds__(256) void k1(const void* h, const float* wsrc,
                                          const float* wdst, _Float16* ssrc_h,
                                          _Float16* sdst_h) {
    __shared__ float hls[16 * 132];
    __shared__ float wls[16 * 132];
    if (probe_is_f32(h)) k1_body<true >(h, wsrc, wdst, ssrc_h, sdst_h, hls, wls);
    else                 k1_body<false>(h, wsrc, wdst, ssrc_h, sdst_h, hls, wls);
}

// ---------------------------------------------------------------------------
// Main fused kernel. 16 nodes/block, 256 threads (4 waves), grid 512.
//   G1 : yln[16x128] = Zbf[16x1024] @ WeffT^T + hs
//        *** BISECTION ROUND: G1 on f32 VALU, reading the IDENTICAL swizzled
//        Zb LDS bytes and IDENTICAL bf16 WeffT global bytes the MFMA version
//        read.  If this passes, the MFMA invocation was the bug; if it fails,
//        the data path (Weff/Z/scores) is. ***
//   FF1/FF2: known-good f32 VALU path
// Zbf is bf16 in LDS, XOR swizzle byte^=((row&7)<<4).
// ---------------------------------------------------------------------------
struct __align__(16) Smem {
    union {
        unsigned short Zb[NB][1024];           // 32768   P4 -> G1 (bf16, swizzled)
        struct {
            float ts[NB][132];                 // 8448    LN1 -> FF1/FF2 (padded)
            float us[NB][260];                 // 16640   FF1 -> FF2 (padded)
            float ys[NB][128];                 // 8192    FF2 -> LN2
        } ff;
    } u;
    float hs[NB][128];                         // 8192    residual
    union {
        float attn[NB][16][8];                 // 8192    P2 -> P4
        float yln[NB][128];                    // 8192    G1 -> LN1
    } v;
    int   nls[NB][16];                         // 1024
    int   adjs[NB][16];                        // 1024
    float ssrc[NB][8];                         // 512
};

template <bool F32>
static __device__ __forceinline__ void gat_body(
        Smem& s,
        const void* __restrict__ h,
        const int*  __restrict__ adj,
        const int*  __restrict__ n_list,
        const _Float16* __restrict__ ssrc_h,
        const _Float16* __restrict__ sdst_h,
        const unsigned short* __restrict__ WeffT,
        const void* __restrict__ g1, const void* __restrict__ bb1,
        const void* __restrict__ w1, const void* __restrict__ fb1,
        const void* __restrict__ w2, const void* __restrict__ fb2,
        const void* __restrict__ g2, const void* __restrict__ bb2,
        void* __restrict__ out) {
    using P = Pol<F32>;
    const int t   = threadIdx.x;
    const int bn0 = blockIdx.x * NB;
    const int b   = bn0 >> 9;                  // 512 nodes per batch

    // ---- P1: self rows + neighbor lists + gathered ssrc
    {
        const int r = t >> 4, c0 = (t & 15) * 8;
        float v[8];
        P::ld8(h, (long)(bn0 + r) * 128 + c0, v);
        #pragma unroll
        for (int j = 0; j < 8; ++j) s.hs[r][c0 + j] = v[j];
    }
    {
        const int r = t >> 4, m = t & 15;
        s.nls[r][m]  = n_list[(bn0 + r) * M_ + m] & (N_ - 1);
        s.adjs[r][m] = adj[(bn0 + r) * M_ + m];
    }
    if (t < NB * 8) s.ssrc[t >> 3][t & 7] = (float)ssrc_h[bn0 * 8 + t];
    __syncthreads();

    // ---- P2: scores = mask(leaky(s_src + s_dst[nl]))
    {
        const int r = t >> 4, m = t & 15;
        const int nbr = s.nls[r][m];
        const f16x8 sd = *(const f16x8*)(sdst_h + (size_t)(b * N_ + nbr) * 8);
        const int amask = s.adjs[r][m];
        float sc[8];
        #pragma unroll
        for (int hh = 0; hh < 8; ++hh) {
            float x = s.ssrc[r][hh] + (float)sd[hh];
            x = x > 0.f ? x : 0.2f * x;        // leaky_relu BEFORE mask (ref order)
            if (amask == 0) x = -1e9f;
            sc[hh] = x;
        }
        *(float4*)&s.v.attn[r][m][0] = make_float4(sc[0], sc[1], sc[2], sc[3]);
        *(float4*)&s.v.attn[r][m][4] = make_float4(sc[4], sc[5], sc[6], sc[7]);
    }
    __syncthreads();

    // ---- P3: softmax over m
    if (t < NB * 8) {
        const int r = t >> 3, hh = t & 7;
        float mx = -3.4e38f;
        #pragma unroll
        for (int m = 0; m < 16; ++m) mx = fmaxf(mx, s.v.attn[r][m][hh]);
        float ex[16], sum = 0.f;
        #pragma unroll
        for (int m = 0; m < 16; ++m) { ex[m] = __expf(s.v.attn[r][m][hh] - mx); sum += ex[m]; }
        const float inv = 1.f / sum;
        #pragma unroll
        for (int m = 0; m < 16; ++m) s.v.attn[r][m][hh] = ex[m] * inv;
    }
    __syncthreads();

    // ---- P4: Z[r][hh][d] = sum_m attn[r][m][hh] * h[nl[r][m]][d]  (bf16, swizzled)
    {
        const int r = t >> 4, dc = t & 15, d0 = dc * 8;
        float z[8][8];
        #pragma unroll
        for (int hh = 0; hh < 8; ++hh)
            #pragma unroll
            for (int jj = 0; jj < 8; ++jj) z[hh][jj] = 0.f;
        #pragma unroll 4
        for (int m = 0; m < 16; ++m) {
            const int nbr = s.nls[r][m];
            float hv[8];
            P::ld8(h, (long)(b * N_ + nbr) * 128 + d0, hv);
            const float4 a0 = *(const float4*)&s.v.attn[r][m][0];
            const float4 a1 = *(const float4*)&s.v.attn[r][m][4];
            const float av[8] = { a0.x, a0.y, a0.z, a0.w, a1.x, a1.y, a1.z, a1.w };
            #pragma unroll
            for (int hh = 0; hh < 8; ++hh)
                #pragma unroll
                for (int jj = 0; jj < 8; ++jj) z[hh][jj] += av[hh] * hv[jj];
        }
        char* zb = (char*)&s.u.Zb[0][0] + r * 2048;
        const int xo = (r & 7) << 4;
        #pragma unroll
        for (int hh = 0; hh < 8; ++hh) {
            u16x8 vv;
            #pragma unroll
            for (int jj = 0; jj < 8; ++jj) vv[jj] = f2bu(z[hh][jj]);
            *(u16x8*)(zb + ((hh * 256 + dc * 16) ^ xo)) = vv;
        }
    }
    __syncthreads();

    // ---- G1 (VALU bisect): yln = Zb @ WeffT^T + hs
    //      thread t: feature e = t&127, rows half*8 .. half*8+7 (half = t>>7)
    {
        const int e    = t & 127;
        const int half = t >> 7;
        float acc[8];
        #pragma unroll
        for (int rr = 0; rr < 8; ++rr) acc[rr] = 0.f;
        const unsigned short* wr = WeffT + (size_t)e * 1024;
        for (int k0 = 0; k0 < 1024; k0 += 8) {
            const u16x8 wv = *(const u16x8*)(wr + k0);
            float wf[8];
            #pragma unroll
            for (int j = 0; j < 8; ++j) wf[j] = bu2f(wv[j]);
            #pragma unroll
            for (int rr = 0; rr < 8; ++rr) {
                const int row = half * 8 + rr;
                const char* zb = (const char*)&s.u.Zb[0][0] + row * 2048;
                const u16x8 zv = *(const u16x8*)(zb + ((k0 * 2) ^ ((row & 7) << 4)));
                #pragma unroll
                for (int j = 0; j < 8; ++j) acc[rr] += bu2f(zv[j]) * wf[j];
            }
        }
        #pragma unroll
        for (int rr = 0; rr < 8; ++rr) {
            const int row = half * 8 + rr;
            s.v.yln[row][e] = acc[rr] + s.hs[row][e];
        }
    }
    __syncthreads();

    // ---- LN1 -> ts (f32, padded rows). 16 threads per row.
    {
        const int r = t >> 4, j0 = (t & 15) * 8;
        const float4 x0 = *(const float4*)&s.v.yln[r][j0];
        const float4 x1 = *(const float4*)&s.v.yln[r][j0 + 4];
        const float x[8] = { x0.x, x0.y, x0.z, x0.w, x1.x, x1.y, x1.z, x1.w };
        float sm = 0.f, ss = 0.f;
        #pragma unroll
        for (int j = 0; j < 8; ++j) { sm += x[j]; ss += x[j] * x[j]; }
        #pragma unroll
        for (int off = 8; off > 0; off >>= 1) {
            sm += __shfl_xor(sm, off);
            ss += __shfl_xor(ss, off);
        }
        const float mu   = sm * (1.f / 128.f);
        const float var  = ss * (1.f / 128.f) - mu * mu;
        const float rstd = rsqrtf(var + 1e-5f);
        float gv[8], bv[8];
        P::ld8(g1, j0, gv);
        P::ld8(bb1, j0, bv);
        #pragma unroll
        for (int j = 0; j < 8; ++j)
            s.u.ff.ts[r][j0 + j] = (x[j] - mu) * rstd * gv[j] + bv[j];
    }
    __syncthreads();

    // ---- FF1: us = relu(ts @ w1 + b1)   (f32 VALU, known-good structure)
    {
        float acc[NB];
        #pragma unroll
        for (int r = 0; r < NB; ++r) acc[r] = 0.f;
        for (int k0 = 0; k0 < 128; k0 += 4) {
            float wv[4];
            #pragma unroll
            for (int j = 0; j < 4; ++j) wv[j] = P::ld(w1, (k0 + j) * 256 + t);
            #pragma unroll
            for (int r = 0; r < NB; ++r) {
                const float4 tv = *(const float4*)&s.u.ff.ts[r][k0];
                acc[r] += tv.x * wv[0] + tv.y * wv[1] + tv.z * wv[2] + tv.w * wv[3];
            }
        }
        const float bias = P::ld(fb1, t);
        #pragma unroll
        for (int r = 0; r < NB; ++r) s.u.ff.us[r][t] = fmaxf(acc[r] + bias, 0.f);
    }
    __syncthreads();

    // ---- FF2: ys = us @ w2 + b2 + ts   (f32 VALU, known-good structure)
    {
        const int e    = t & 127;
        const int half = t >> 7;              // 8 rows per thread
        float acc[8];
        #pragma unroll
        for (int rr = 0; rr < 8; ++rr) acc[rr] = 0.f;
        for (int k0 = 0; k0 < 256; k0 += 4) {
            float wv[4];
            #pragma unroll
            for (int j = 0; j < 4; ++j) wv[j] = P::ld(w2, (k0 + j) * 128 + e);
            #pragma unroll
            for (int rr = 0; rr < 8; ++rr) {
                const float4 uv = *(const float4*)&s.u.ff.us[half * 8 + rr][k0];
                acc[rr] += uv.x * wv[0] + uv.y * wv[1] + uv.z * wv[2] + uv.w * wv[3];
            }
        }
        const float bias = P::ld(fb2, e);
        #pragma unroll
        for (int rr = 0; rr < 8; ++rr) {
            const int r = half * 8 + rr;
            s.u.ff.ys[r][e] = acc[rr] + bias + s.u.ff.ts[r][e];
        }
    }
    __syncthreads();

    // ---- LN2 -> out. 16 threads per row.
    {
        const int r = t >> 4, j0 = (t & 15) * 8;
        const float4 x0 = *(const float4*)&s.u.ff.ys[r][j0];
        const float4 x1 = *(const float4*)&s.u.ff.ys[r][j0 + 4];
        const float x[8] = { x0.x, x0.y, x0.z, x0.w, x1.x, x1.y, x1.z, x1.w };
        float sm = 0.f, ss = 0.f;
        #pragma unroll
        for (int j = 0; j < 8; ++j) { sm += x[j]; ss += x[j] * x[j]; }
        #pragma unroll
        for (int off = 8; off > 0; off >>= 1) {
            sm += __shfl_xor(sm, off);
            ss += __shfl_xor(ss, off);
        }
        const float mu   = sm * (1.f / 128.f);
        const float var  = ss * (1.f / 128.f) - mu * mu;
        const float rstd = rsqrtf(var + 1e-5f);
        float gv[8], bv[8], o8[8];
        P::ld8(g2, j0, gv);
        P::ld8(bb2, j0, bv);
        #pragma unroll
        for (int j = 0; j < 8; ++j) o8[j] = (x[j] - mu) * rstd * gv[j] + bv[j];
        P::st8(out, (long)(bn0 + r) * 128 + j0, o8);
    }
}

__global__ __launch_bounds__(256) void k_gat(
        const void* __restrict__ h,
        const int*  __restrict__ adj,
        const int*  __restrict__ n_list,
        const _Float16* __restrict__ ssrc_h,
        const _Float16* __restrict__ sdst_h,
        const unsigned short* __restrict__ WeffT,
        const void* __restrict__ g1, const void* __restrict__ bb1,
        const void* __restrict__ w1, const void* __restrict__ fb1,
        const void* __restrict__ w2, const void* __restrict__ fb2,
        const void* __restrict__ g2, const void* __restrict__ bb2,
        void* __restrict__ out) {
    __shared__ Smem s;
    if (probe_is_f32(h))
        gat_body<true >(s, h, adj, n_list, ssrc_h, sdst_h, WeffT,
                        g1, bb1, w1, fb1, w2, fb2, g2, bb2, out);
    else
        gat_body<false>(s, h, adj, n_list, ssrc_h, sdst_h, WeffT,
                        g1, bb1, w1, fb1, w2, fb2, g2, bb2, out);
}

// ---------------------------------------------------------------------------
extern "C" void kernel_launch(void* const* d_in, const int* in_sizes, int n_in,
                              void* d_out, int out_size, void* d_ws, size_t ws_size,
                              hipStream_t stream) {
    (void)in_sizes; (void)n_in; (void)out_size; (void)ws_size;

    // ws layout (bytes) — total 532480, identical footprint to the proven kernel:
    //   wsrc   [     0,   4096)  f32[1024]
    //   wdst   [  4096,   8192)  f32[1024]
    //   ssrc   [  8192, 139264)  f16[8192*8]
    //   sdst   [139264, 270336)  f16[8192*8]
    //   WeffT  [270336, 532480)  bf16[128][1024]
    char* wsb = (char*)d_ws;
    float*          wsrc  = (float*)(wsb);
    float*          wdst  = (float*)(wsb + 4096);
    _Float16*       ssrc  = (_Float16*)(wsb + 8192);
    _Float16*       sdst  = (_Float16*)(wsb + 139264);
    unsigned short* WeffT = (unsigned short*)(wsb + 270336);

    k0<<<520,      256, 0, stream>>>(d_in[3], d_in[6], d_in[4], d_in[5], d_in[0],
                                     wsrc, wdst, WeffT);
    k1<<<BN_ / 16, 256, 0, stream>>>(d_in[0], wsrc, wdst, ssrc, sdst);
    k_gat<<<BN_ / NB, 256, 0, stream>>>(
        d_in[0], (const int*)d_in[1], (const int*)d_in[2], ssrc, sdst, WeffT,
        d_in[7], d_in[8], d_in[9], d_in[10], d_in[11], d_in[12],
        d_in[13], d_in[14], d_out);
}

// Round 4
// 174.164 us; speedup vs baseline: 1.6931x; 1.1708x over previous
//
#include <hip/hip_runtime.h>
#include <hip/hip_bf16.h>

// Problem constants
#define B_  16
#define N_  512
#define M_  16
#define H_  8
#define D_  128
#define BN_ 8192   // B_*N_
#define NB  16     // nodes per block in main kernel

typedef __attribute__((ext_vector_type(4))) float          f32x4;
typedef __attribute__((ext_vector_type(4))) _Float16       f16x4;
typedef __attribute__((ext_vector_type(8))) unsigned short u16x8;
typedef __attribute__((ext_vector_type(8))) _Float16       f16x8;

static __device__ __forceinline__ float bf2f(__hip_bfloat16 x) { return __bfloat162float(x); }
static __device__ __forceinline__ unsigned short f2bu(float x) {
    __hip_bfloat16 b = __float2bfloat16(x);
    return *reinterpret_cast<unsigned short*>(&b);
}
static __device__ __forceinline__ float bu2f(unsigned short u) {
    return __uint_as_float(((unsigned int)u) << 16);
}

// Load/store policy: interpret float tensors as f32 or bf16.
template <bool F32>
struct Pol {
    static __device__ __forceinline__ float ld(const void* p, int i) {
        if constexpr (F32) return ((const float*)p)[i];
        else               return bf2f(((const __hip_bfloat16*)p)[i]);
    }
    static __device__ __forceinline__ float4 ld4(const void* p, int i) {  // i%4==0
        if constexpr (F32) return *(const float4*)((const float*)p + i);
        else {
            const ushort4 u = *(const ushort4*)((const unsigned short*)p + i);
            return make_float4(bu2f(u.x), bu2f(u.y), bu2f(u.z), bu2f(u.w));
        }
    }
    static __device__ __forceinline__ void ld8(const void* p, long i, float* v) {  // i%8==0
        if constexpr (F32) {
            const float4 a = *(const float4*)((const float*)p + i);
            const float4 b = *(const float4*)((const float*)p + i + 4);
            v[0]=a.x; v[1]=a.y; v[2]=a.z; v[3]=a.w;
            v[4]=b.x; v[5]=b.y; v[6]=b.z; v[7]=b.w;
        } else {
            const u16x8 u = *(const u16x8*)((const unsigned short*)p + i);
            #pragma unroll
            for (int j = 0; j < 8; ++j) v[j] = bu2f(u[j]);
        }
    }
    static __device__ __forceinline__ void st8(void* p, long i, const float* v) {  // i%8==0
        if constexpr (F32) {
            *(float4*)((float*)p + i)     = make_float4(v[0], v[1], v[2], v[3]);
            *(float4*)((float*)p + i + 4) = make_float4(v[4], v[5], v[6], v[7]);
        } else {
            u16x8 u;
            #pragma unroll
            for (int j = 0; j < 8; ++j) u[j] = f2bu(v[j]);
            *(u16x8*)((unsigned short*)p + i) = u;
        }
    }
};

// Dtype probe (verbatim): f32 buffers read as bf16 at even index give
// random-exponent garbage; genuine bf16 stays small.
static __device__ __forceinline__ bool probe_is_f32(const void* h) {
    bool is_f32 = false;
    const __hip_bfloat16* hb = (const __hip_bfloat16*)h;
    for (int i = 0; i < 128; ++i) {
        const float v = bf2f(hb[2 * i]);
        if (!(fabsf(v) < 1e4f)) is_f32 = true;
    }
    return is_f32;
}

// ---------------------------------------------------------------------------
// K0 (prep, grid 520):
//   blk <  512 : WeffT[o][hd] = f16( sum_e W[hd][e] * Wo[(h*128+e)][o] )
//                (2 hd rows per block; hd = h*128+d)
//   blk >= 512 : wsrc/wdst[h][d] = sum_e W[h][d][e] * a_{src,dst}[h][e]  (f32)
// ---------------------------------------------------------------------------
template <bool F32>
static __device__ __forceinline__ void k0_body(
        const void* __restrict__ W,  const void* __restrict__ Wo,
        const void* __restrict__ a_src, const void* __restrict__ a_dst,
        float* __restrict__ wsrc, float* __restrict__ wdst,
        _Float16* __restrict__ WeffT, float* wrow /* shared [2*128] */) {
    using P = Pol<F32>;
    const int blk = blockIdx.x;
    const int t   = threadIdx.x;
    if (blk < 512) {
        const int half = t >> 7, o = t & 127;
        const int hd = blk * 2 + half;               // hd = h*128 + d
        wrow[half * 128 + o] = P::ld(W, hd * 128 + o);
        __syncthreads();
        const int hh = hd >> 7;
        float acc = 0.f;
        #pragma unroll 8
        for (int e = 0; e < 128; ++e)
            acc += wrow[half * 128 + e] * P::ld(Wo, (hh * 128 + e) * 128 + o);
        WeffT[(size_t)o * 1024 + hd] = (_Float16)acc;
    } else {
        const int hh = blk - 512;
        const int which = t >> 7, d = t & 127;
        const void* av = which ? a_dst : a_src;
        const int wbase = hh * (D_ * D_) + d * 128;
        float acc = 0.f;
        #pragma unroll 8
        for (int e = 0; e < 128; e += 4) {
            const float4 wv = P::ld4(W, wbase + e);
            const float4 aa = P::ld4(av, hh * 128 + e);
            acc += wv.x * aa.x + wv.y * aa.y + wv.z * aa.z + wv.w * aa.w;
        }
        (which ? wdst : wsrc)[hh * 128 + d] = acc;
    }
}

__global__ __launch_bounds__(256) void k0(
        const void* W, const void* Wo, const void* a_src, const void* a_dst,
        const void* h, float* wsrc, float* wdst, _Float16* WeffT) {
    __shared__ float wrow[2 * 128];
    if (probe_is_f32(h)) k0_body<true >(W, Wo, a_src, a_dst, wsrc, wdst, WeffT, wrow);
    else                 k0_body<false>(W, Wo, a_src, a_dst, wsrc, wdst, WeffT, wrow);
}

// ---------------------------------------------------------------------------
// K1: scores.  16 nodes/block; stage h-rows + wsrc/wdst in LDS (padded rows),
// then one f32 dot per (node, head, src/dst) thread.  Outputs f16.
// grid 512 x 256.
// ---------------------------------------------------------------------------
template <bool F32>
static __device__ __forceinline__ void k1_body(
        const void* __restrict__ h, const float* __restrict__ wsrc,
        const float* __restrict__ wdst, _Float16* __restrict__ ssrc_h,
        _Float16* __restrict__ sdst_h, float* hls /*[16*132]*/, float* wls /*[16*132]*/) {
    using P = Pol<F32>;
    const int t   = threadIdx.x;
    const int bn0 = blockIdx.x * 16;
    {
        const int r = t >> 4, c0 = (t & 15) * 8;
        float v[8];
        P::ld8(h, (long)(bn0 + r) * 128 + c0, v);
        #pragma unroll
        for (int j = 0; j < 8; ++j) hls[r * 132 + c0 + j] = v[j];
        const int c = t >> 4;                         // c = which*8 + head
        const float* wp = (c >> 3) ? wdst : wsrc;
        const int woff = (c & 7) * 128 + c0;
        #pragma unroll
        for (int j = 0; j < 8; ++j) wls[c * 132 + c0 + j] = wp[woff + j];
    }
    __syncthreads();
    const int n = t >> 4, c = t & 15;
    float acc = 0.f;
    #pragma unroll
    for (int e = 0; e < 128; e += 4) {
        const float4 hv = *(const float4*)(hls + n * 132 + e);
        const float4 wv = *(const float4*)(wls + c * 132 + e);
        acc += hv.x * wv.x + hv.y * wv.y + hv.z * wv.z + hv.w * wv.w;
    }
    const int node = bn0 + n;
    if (c < 8) ssrc_h[node * 8 + c]       = (_Float16)acc;
    else       sdst_h[node * 8 + (c - 8)] = (_Float16)acc;
}

__global__ __launch_bounds__(256) void k1(const void* h, const float* wsrc,
                                          const float* wdst, _Float16* ssrc_h,
                                          _Float16* sdst_h) {
    __shared__ float hls[16 * 132];
    __shared__ float wls[16 * 132];
    if (probe_is_f32(h)) k1_body<true >(h, wsrc, wdst, ssrc_h, sdst_h, hls, wls);
    else                 k1_body<false>(h, wsrc, wdst, ssrc_h, sdst_h, hls, wls);
}

// ---------------------------------------------------------------------------
// Main fused kernel. 16 nodes/block, 256 threads (4 waves), grid 512.
//   G1 : yln[16x128] = Zh[16x1024] @ WeffT^T + hs
//        *** MFMA via v_mfma_f32_16x16x16_f16 (classic, lab-notes layout:
//        A row=l&15 k=4*(l>>4)+j; B col=l&15 same k; D reg q -> row
//        4*(l>>4)+q, col l&15).  K=16/instruction removes the x32
//        instruction's k-grouping ambiguity that failed rounds 1-2. ***
//   FF1/FF2: known-good f32 VALU path
// Zh is f16 in LDS, XOR swizzle byte^=((row&7)<<4).
// ---------------------------------------------------------------------------
struct __align__(16) Smem {
    union {
        _Float16 Zh[NB][1024];                 // 32768   P4 -> G1 (f16, swizzled)
        struct {
            float ts[NB][132];                 // 8448    LN1 -> FF1/FF2 (padded)
            float us[NB][260];                 // 16640   FF1 -> FF2 (padded)
            float ys[NB][128];                 // 8192    FF2 -> LN2
        } ff;
    } u;
    float hs[NB][128];                         // 8192    residual
    union {
        float attn[NB][16][8];                 // 8192    P2 -> P4
        float yln[NB][128];                    // 8192    G1 -> LN1
    } v;
    int   nls[NB][16];                         // 1024
    int   adjs[NB][16];                        // 1024
    float ssrc[NB][8];                         // 512
};

template <bool F32>
static __device__ __forceinline__ void gat_body(
        Smem& s,
        const void* __restrict__ h,
        const int*  __restrict__ adj,
        const int*  __restrict__ n_list,
        const _Float16* __restrict__ ssrc_h,
        const _Float16* __restrict__ sdst_h,
        const _Float16* __restrict__ WeffT,
        const void* __restrict__ g1, const void* __restrict__ bb1,
        const void* __restrict__ w1, const void* __restrict__ fb1,
        const void* __restrict__ w2, const void* __restrict__ fb2,
        const void* __restrict__ g2, const void* __restrict__ bb2,
        void* __restrict__ out) {
    using P = Pol<F32>;
    const int t   = threadIdx.x;
    const int bn0 = blockIdx.x * NB;
    const int b   = bn0 >> 9;                  // 512 nodes per batch
    const int l   = t & 63;
    const int w   = t >> 6;
    const int lo  = l & 15;
    const int hi  = l >> 4;

    // ---- P1: self rows + neighbor lists + gathered ssrc
    {
        const int r = t >> 4, c0 = (t & 15) * 8;
        float v[8];
        P::ld8(h, (long)(bn0 + r) * 128 + c0, v);
        #pragma unroll
        for (int j = 0; j < 8; ++j) s.hs[r][c0 + j] = v[j];
    }
    {
        const int r = t >> 4, m = t & 15;
        s.nls[r][m]  = n_list[(bn0 + r) * M_ + m] & (N_ - 1);
        s.adjs[r][m] = adj[(bn0 + r) * M_ + m];
    }
    if (t < NB * 8) s.ssrc[t >> 3][t & 7] = (float)ssrc_h[bn0 * 8 + t];
    __syncthreads();

    // ---- P2: scores = mask(leaky(s_src + s_dst[nl]))
    {
        const int r = t >> 4, m = t & 15;
        const int nbr = s.nls[r][m];
        const f16x8 sd = *(const f16x8*)(sdst_h + (size_t)(b * N_ + nbr) * 8);
        const int amask = s.adjs[r][m];
        float sc[8];
        #pragma unroll
        for (int hh = 0; hh < 8; ++hh) {
            float x = s.ssrc[r][hh] + (float)sd[hh];
            x = x > 0.f ? x : 0.2f * x;        // leaky_relu BEFORE mask (ref order)
            if (amask == 0) x = -1e9f;
            sc[hh] = x;
        }
        *(float4*)&s.v.attn[r][m][0] = make_float4(sc[0], sc[1], sc[2], sc[3]);
        *(float4*)&s.v.attn[r][m][4] = make_float4(sc[4], sc[5], sc[6], sc[7]);
    }
    __syncthreads();

    // ---- P3: softmax over m
    if (t < NB * 8) {
        const int r = t >> 3, hh = t & 7;
        float mx = -3.4e38f;
        #pragma unroll
        for (int m = 0; m < 16; ++m) mx = fmaxf(mx, s.v.attn[r][m][hh]);
        float ex[16], sum = 0.f;
        #pragma unroll
        for (int m = 0; m < 16; ++m) { ex[m] = __expf(s.v.attn[r][m][hh] - mx); sum += ex[m]; }
        const float inv = 1.f / sum;
        #pragma unroll
        for (int m = 0; m < 16; ++m) s.v.attn[r][m][hh] = ex[m] * inv;
    }
    __syncthreads();

    // ---- P4: Z[r][hh][d] = sum_m attn[r][m][hh] * h[nl[r][m]][d]  (f16, swizzled)
    {
        const int r = t >> 4, dc = t & 15, d0 = dc * 8;
        float z[8][8];
        #pragma unroll
        for (int hh = 0; hh < 8; ++hh)
            #pragma unroll
            for (int jj = 0; jj < 8; ++jj) z[hh][jj] = 0.f;
        #pragma unroll 4
        for (int m = 0; m < 16; ++m) {
            const int nbr = s.nls[r][m];
            float hv[8];
            P::ld8(h, (long)(b * N_ + nbr) * 128 + d0, hv);
            const float4 a0 = *(const float4*)&s.v.attn[r][m][0];
            const float4 a1 = *(const float4*)&s.v.attn[r][m][4];
            const float av[8] = { a0.x, a0.y, a0.z, a0.w, a1.x, a1.y, a1.z, a1.w };
            #pragma unroll
            for (int hh = 0; hh < 8; ++hh)
                #pragma unroll
                for (int jj = 0; jj < 8; ++jj) z[hh][jj] += av[hh] * hv[jj];
        }
        char* zb = (char*)&s.u.Zh[0][0] + r * 2048;
        const int xo = (r & 7) << 4;
        #pragma unroll
        for (int hh = 0; hh < 8; ++hh) {
            f16x8 vv;
            #pragma unroll
            for (int jj = 0; jj < 8; ++jj) vv[jj] = (_Float16)z[hh][jj];
            *(f16x8*)(zb + ((hh * 256 + dc * 16) ^ xo)) = vv;
        }
    }
    __syncthreads();

    // ---- G1: yln = Zh @ WeffT^T + hs   (f16 MFMA 16x16x16, K=1024)
    //      wave w covers output cols [w*32, w*32+32); lane l: row-src lo, k-grp hi
    {
        const char* za  = (const char*)&s.u.Zh[0][0] + lo * 2048;
        const int   xo  = (lo & 7) << 4;
        const char* wb0 = (const char*)(WeffT + (size_t)(w * 32 + lo)      * 1024);
        const char* wb1 = (const char*)(WeffT + (size_t)(w * 32 + lo + 16) * 1024);
        f32x4 acc0 = {0.f, 0.f, 0.f, 0.f}, acc1 = {0.f, 0.f, 0.f, 0.f};
        #pragma unroll 8
        for (int ks = 0; ks < 64; ++ks) {
            const int kb = ks * 32 + hi * 8;           // byte offset of k = ks*16 + hi*4
            const f16x4 a  = *(const f16x4*)(za + (kb ^ xo));
            const f16x4 b0 = *(const f16x4*)(wb0 + kb);
            const f16x4 b1 = *(const f16x4*)(wb1 + kb);
            acc0 = __builtin_amdgcn_mfma_f32_16x16x16f16(a, b0, acc0, 0, 0, 0);
            acc1 = __builtin_amdgcn_mfma_f32_16x16x16f16(a, b1, acc1, 0, 0, 0);
        }
        const int o0 = w * 32 + lo, o1 = o0 + 16;
        #pragma unroll
        for (int q = 0; q < 4; ++q) {
            const int rr = hi * 4 + q;
            s.v.yln[rr][o0] = acc0[q] + s.hs[rr][o0];
            s.v.yln[rr][o1] = acc1[q] + s.hs[rr][o1];
        }
    }
    __syncthreads();

    // ---- LN1 -> ts (f32, padded rows). 16 threads per row.
    {
        const int r = t >> 4, j0 = (t & 15) * 8;
        const float4 x0 = *(const float4*)&s.v.yln[r][j0];
        const float4 x1 = *(const float4*)&s.v.yln[r][j0 + 4];
        const float x[8] = { x0.x, x0.y, x0.z, x0.w, x1.x, x1.y, x1.z, x1.w };
        float sm = 0.f, ss = 0.f;
        #pragma unroll
        for (int j = 0; j < 8; ++j) { sm += x[j]; ss += x[j] * x[j]; }
        #pragma unroll
        for (int off = 8; off > 0; off >>= 1) {
            sm += __shfl_xor(sm, off);
            ss += __shfl_xor(ss, off);
        }
        const float mu   = sm * (1.f / 128.f);
        const float var  = ss * (1.f / 128.f) - mu * mu;
        const float rstd = rsqrtf(var + 1e-5f);
        float gv[8], bv[8];
        P::ld8(g1, j0, gv);
        P::ld8(bb1, j0, bv);
        #pragma unroll
        for (int j = 0; j < 8; ++j)
            s.u.ff.ts[r][j0 + j] = (x[j] - mu) * rstd * gv[j] + bv[j];
    }
    __syncthreads();

    // ---- FF1: us = relu(ts @ w1 + b1)   (f32 VALU, known-good structure)
    {
        float acc[NB];
        #pragma unroll
        for (int r = 0; r < NB; ++r) acc[r] = 0.f;
        for (int k0 = 0; k0 < 128; k0 += 4) {
            float wv[4];
            #pragma unroll
            for (int j = 0; j < 4; ++j) wv[j] = P::ld(w1, (k0 + j) * 256 + t);
            #pragma unroll
            for (int r = 0; r < NB; ++r) {
                const float4 tv = *(const float4*)&s.u.ff.ts[r][k0];
                acc[r] += tv.x * wv[0] + tv.y * wv[1] + tv.z * wv[2] + tv.w * wv[3];
            }
        }
        const float bias = P::ld(fb1, t);
        #pragma unroll
        for (int r = 0; r < NB; ++r) s.u.ff.us[r][t] = fmaxf(acc[r] + bias, 0.f);
    }
    __syncthreads();

    // ---- FF2: ys = us @ w2 + b2 + ts   (f32 VALU, known-good structure)
    {
        const int e    = t & 127;
        const int half = t >> 7;              // 8 rows per thread
        float acc[8];
        #pragma unroll
        for (int rr = 0; rr < 8; ++rr) acc[rr] = 0.f;
        for (int k0 = 0; k0 < 256; k0 += 4) {
            float wv[4];
            #pragma unroll
            for (int j = 0; j < 4; ++j) wv[j] = P::ld(w2, (k0 + j) * 128 + e);
            #pragma unroll
            for (int rr = 0; rr < 8; ++rr) {
                const float4 uv = *(const float4*)&s.u.ff.us[half * 8 + rr][k0];
                acc[rr] += uv.x * wv[0] + uv.y * wv[1] + uv.z * wv[2] + uv.w * wv[3];
            }
        }
        const float bias = P::ld(fb2, e);
        #pragma unroll
        for (int rr = 0; rr < 8; ++rr) {
            const int r = half * 8 + rr;
            s.u.ff.ys[r][e] = acc[rr] + bias + s.u.ff.ts[r][e];
        }
    }
    __syncthreads();

    // ---- LN2 -> out. 16 threads per row.
    {
        const int r = t >> 4, j0 = (t & 15) * 8;
        const float4 x0 = *(const float4*)&s.u.ff.ys[r][j0];
        const float4 x1 = *(const float4*)&s.u.ff.ys[r][j0 + 4];
        const float x[8] = { x0.x, x0.y, x0.z, x0.w, x1.x, x1.y, x1.z, x1.w };
        float sm = 0.f, ss = 0.f;
        #pragma unroll
        for (int j = 0; j < 8; ++j) { sm += x[j]; ss += x[j] * x[j]; }
        #pragma unroll
        for (int off = 8; off > 0; off >>= 1) {
            sm += __shfl_xor(sm, off);
            ss += __shfl_xor(ss, off);
        }
        const float mu   = sm * (1.f / 128.f);
        const float var  = ss * (1.f / 128.f) - mu * mu;
        const float rstd = rsqrtf(var + 1e-5f);
        float gv[8], bv[8], o8[8];
        P::ld8(g2, j0, gv);
        P::ld8(bb2, j0, bv);
        #pragma unroll
        for (int j = 0; j < 8; ++j) o8[j] = (x[j] - mu) * rstd * gv[j] + bv[j];
        P::st8(out, (long)(bn0 + r) * 128 + j0, o8);
    }
}

__global__ __launch_bounds__(256) void k_gat(
        const void* __restrict__ h,
        const int*  __restrict__ adj,
        const int*  __restrict__ n_list,
        const _Float16* __restrict__ ssrc_h,
        const _Float16* __restrict__ sdst_h,
        const _Float16* __restrict__ WeffT,
        const void* __restrict__ g1, const void* __restrict__ bb1,
        const void* __restrict__ w1, const void* __restrict__ fb1,
        const void* __restrict__ w2, const void* __restrict__ fb2,
        const void* __restrict__ g2, const void* __restrict__ bb2,
        void* __restrict__ out) {
    __shared__ Smem s;
    if (probe_is_f32(h))
        gat_body<true >(s, h, adj, n_list, ssrc_h, sdst_h, WeffT,
                        g1, bb1, w1, fb1, w2, fb2, g2, bb2, out);
    else
        gat_body<false>(s, h, adj, n_list, ssrc_h, sdst_h, WeffT,
                        g1, bb1, w1, fb1, w2, fb2, g2, bb2, out);
}

// ---------------------------------------------------------------------------
extern "C" void kernel_launch(void* const* d_in, const int* in_sizes, int n_in,
                              void* d_out, int out_size, void* d_ws, size_t ws_size,
                              hipStream_t stream) {
    (void)in_sizes; (void)n_in; (void)out_size; (void)ws_size;

    // ws layout (bytes) — total 532480, identical footprint to the proven kernel:
    //   wsrc   [     0,   4096)  f32[1024]
    //   wdst   [  4096,   8192)  f32[1024]
    //   ssrc   [  8192, 139264)  f16[8192*8]
    //   sdst   [139264, 270336)  f16[8192*8]
    //   WeffT  [270336, 532480)  f16[128][1024]
    char* wsb = (char*)d_ws;
    float*     wsrc  = (float*)(wsb);
    float*     wdst  = (float*)(wsb + 4096);
    _Float16*  ssrc  = (_Float16*)(wsb + 8192);
    _Float16*  sdst  = (_Float16*)(wsb + 139264);
    _Float16*  WeffT = (_Float16*)(wsb + 270336);

    k0<<<520,      256, 0, stream>>>(d_in[3], d_in[6], d_in[4], d_in[5], d_in[0],
                                     wsrc, wdst, WeffT);
    k1<<<BN_ / 16, 256, 0, stream>>>(d_in[0], wsrc, wdst, ssrc, sdst);
    k_gat<<<BN_ / NB, 256, 0, stream>>>(
        d_in[0], (const int*)d_in[1], (const int*)d_in[2], ssrc, sdst, WeffT,
        d_in[7], d_in[8], d_in[9], d_in[10], d_in[11], d_in[12],
        d_in[13], d_in[14], d_out);
}

// Round 5
// 158.880 us; speedup vs baseline: 1.8559x; 1.0962x over previous
//
#include <hip/hip_runtime.h>
#include <hip/hip_bf16.h>

// Problem constants
#define B_  16
#define N_  512
#define M_  16
#define H_  8
#define D_  128
#define BN_ 8192   // B_*N_
#define NB  16     // nodes per block in main kernel

typedef __attribute__((ext_vector_type(4))) float          f32x4;
typedef __attribute__((ext_vector_type(4))) _Float16       f16x4;
typedef __attribute__((ext_vector_type(8))) unsigned short u16x8;
typedef __attribute__((ext_vector_type(8))) _Float16       f16x8;

static __device__ __forceinline__ float bf2f(__hip_bfloat16 x) { return __bfloat162float(x); }
static __device__ __forceinline__ unsigned short f2bu(float x) {
    __hip_bfloat16 b = __float2bfloat16(x);
    return *reinterpret_cast<unsigned short*>(&b);
}
static __device__ __forceinline__ float bu2f(unsigned short u) {
    return __uint_as_float(((unsigned int)u) << 16);
}

// Load/store policy: interpret float tensors as f32 or bf16.
template <bool F32>
struct Pol {
    static __device__ __forceinline__ float ld(const void* p, int i) {
        if constexpr (F32) return ((const float*)p)[i];
        else               return bf2f(((const __hip_bfloat16*)p)[i]);
    }
    static __device__ __forceinline__ float4 ld4(const void* p, int i) {  // i%4==0
        if constexpr (F32) return *(const float4*)((const float*)p + i);
        else {
            const ushort4 u = *(const ushort4*)((const unsigned short*)p + i);
            return make_float4(bu2f(u.x), bu2f(u.y), bu2f(u.z), bu2f(u.w));
        }
    }
    static __device__ __forceinline__ void ld8(const void* p, long i, float* v) {  // i%8==0
        if constexpr (F32) {
            const float4 a = *(const float4*)((const float*)p + i);
            const float4 b = *(const float4*)((const float*)p + i + 4);
            v[0]=a.x; v[1]=a.y; v[2]=a.z; v[3]=a.w;
            v[4]=b.x; v[5]=b.y; v[6]=b.z; v[7]=b.w;
        } else {
            const u16x8 u = *(const u16x8*)((const unsigned short*)p + i);
            #pragma unroll
            for (int j = 0; j < 8; ++j) v[j] = bu2f(u[j]);
        }
    }
    static __device__ __forceinline__ void st8(void* p, long i, const float* v) {  // i%8==0
        if constexpr (F32) {
            *(float4*)((float*)p + i)     = make_float4(v[0], v[1], v[2], v[3]);
            *(float4*)((float*)p + i + 4) = make_float4(v[4], v[5], v[6], v[7]);
        } else {
            u16x8 u;
            #pragma unroll
            for (int j = 0; j < 8; ++j) u[j] = f2bu(v[j]);
            *(u16x8*)((unsigned short*)p + i) = u;
        }
    }
};

// Dtype probe (verbatim): f32 buffers read as bf16 at even index give
// random-exponent garbage; genuine bf16 stays small.
static __device__ __forceinline__ bool probe_is_f32(const void* h) {
    bool is_f32 = false;
    const __hip_bfloat16* hb = (const __hip_bfloat16*)h;
    for (int i = 0; i < 128; ++i) {
        const float v = bf2f(hb[2 * i]);
        if (!(fabsf(v) < 1e4f)) is_f32 = true;
    }
    return is_f32;
}

// ---------------------------------------------------------------------------
// K0 (prep, grid 520):  [byte-identical to passing round 4]
//   blk <  512 : WeffT[o][hd] = f16( sum_e W[hd][e] * Wo[(h*128+e)][o] )
//   blk >= 512 : wsrc/wdst[h][d] = sum_e W[h][d][e] * a_{src,dst}[h][e]  (f32)
// ---------------------------------------------------------------------------
template <bool F32>
static __device__ __forceinline__ void k0_body(
        const void* __restrict__ W,  const void* __restrict__ Wo,
        const void* __restrict__ a_src, const void* __restrict__ a_dst,
        float* __restrict__ wsrc, float* __restrict__ wdst,
        _Float16* __restrict__ WeffT, float* wrow /* shared [2*128] */) {
    using P = Pol<F32>;
    const int blk = blockIdx.x;
    const int t   = threadIdx.x;
    if (blk < 512) {
        const int half = t >> 7, o = t & 127;
        const int hd = blk * 2 + half;               // hd = h*128 + d
        wrow[half * 128 + o] = P::ld(W, hd * 128 + o);
        __syncthreads();
        const int hh = hd >> 7;
        float acc = 0.f;
        #pragma unroll 8
        for (int e = 0; e < 128; ++e)
            acc += wrow[half * 128 + e] * P::ld(Wo, (hh * 128 + e) * 128 + o);
        WeffT[(size_t)o * 1024 + hd] = (_Float16)acc;
    } else {
        const int hh = blk - 512;
        const int which = t >> 7, d = t & 127;
        const void* av = which ? a_dst : a_src;
        const int wbase = hh * (D_ * D_) + d * 128;
        float acc = 0.f;
        #pragma unroll 8
        for (int e = 0; e < 128; e += 4) {
            const float4 wv = P::ld4(W, wbase + e);
            const float4 aa = P::ld4(av, hh * 128 + e);
            acc += wv.x * aa.x + wv.y * aa.y + wv.z * aa.z + wv.w * aa.w;
        }
        (which ? wdst : wsrc)[hh * 128 + d] = acc;
    }
}

__global__ __launch_bounds__(256) void k0(
        const void* W, const void* Wo, const void* a_src, const void* a_dst,
        const void* h, float* wsrc, float* wdst, _Float16* WeffT) {
    __shared__ float wrow[2 * 128];
    if (probe_is_f32(h)) k0_body<true >(W, Wo, a_src, a_dst, wsrc, wdst, WeffT, wrow);
    else                 k0_body<false>(W, Wo, a_src, a_dst, wsrc, wdst, WeffT, wrow);
}

// ---------------------------------------------------------------------------
// K1: scores.  [byte-identical to passing round 4]
// ---------------------------------------------------------------------------
template <bool F32>
static __device__ __forceinline__ void k1_body(
        const void* __restrict__ h, const float* __restrict__ wsrc,
        const float* __restrict__ wdst, _Float16* __restrict__ ssrc_h,
        _Float16* __restrict__ sdst_h, float* hls /*[16*132]*/, float* wls /*[16*132]*/) {
    using P = Pol<F32>;
    const int t   = threadIdx.x;
    const int bn0 = blockIdx.x * 16;
    {
        const int r = t >> 4, c0 = (t & 15) * 8;
        float v[8];
        P::ld8(h, (long)(bn0 + r) * 128 + c0, v);
        #pragma unroll
        for (int j = 0; j < 8; ++j) hls[r * 132 + c0 + j] = v[j];
        const int c = t >> 4;                         // c = which*8 + head
        const float* wp = (c >> 3) ? wdst : wsrc;
        const int woff = (c & 7) * 128 + c0;
        #pragma unroll
        for (int j = 0; j < 8; ++j) wls[c * 132 + c0 + j] = wp[woff + j];
    }
    __syncthreads();
    const int n = t >> 4, c = t & 15;
    float acc = 0.f;
    #pragma unroll
    for (int e = 0; e < 128; e += 4) {
        const float4 hv = *(const float4*)(hls + n * 132 + e);
        const float4 wv = *(const float4*)(wls + c * 132 + e);
        acc += hv.x * wv.x + hv.y * wv.y + hv.z * wv.z + hv.w * wv.w;
    }
    const int node = bn0 + n;
    if (c < 8) ssrc_h[node * 8 + c]       = (_Float16)acc;
    else       sdst_h[node * 8 + (c - 8)] = (_Float16)acc;
}

__global__ __launch_bounds__(256) void k1(const void* h, const float* wsrc,
                                          const float* wdst, _Float16* ssrc_h,
                                          _Float16* sdst_h) {
    __shared__ float hls[16 * 132];
    __shared__ float wls[16 * 132];
    if (probe_is_f32(h)) k1_body<true >(h, wsrc, wdst, ssrc_h, sdst_h, hls, wls);
    else                 k1_body<false>(h, wsrc, wdst, ssrc_h, sdst_h, hls, wls);
}

// ---------------------------------------------------------------------------
// Main fused kernel. 16 nodes/block, 512 threads (8 waves), grid 512.
// All GEMMs on the PROVEN v_mfma_f32_16x16x16_f16 layout:
//   A lane(lo,hi) reg j = A[lo][4*hi+j]; B = B[4*hi+j][lo]; D reg q -> row
//   4*hi+q, col lo.
//   G1 : yln = Zh[16x1024] @ WeffT^T + hs        (B from ws, f16)
//   FF1: us  = relu(ts @ w1 + b1)                (B direct from w1 + cvt)
//   FF2: ys  = us @ w2 + b2 + ts                 (B direct from w2 + cvt)
// Zh f16 in LDS, XOR swizzle byte^=((row&7)<<4).  LDS = 52224 B.
// ---------------------------------------------------------------------------
struct __align__(16) Smem {
    union {
        _Float16 Zh[NB][1024];                 // 32768   P4 -> G1 (f16, swizzled)
        struct {
            float    ts[NB][132];              // 8448    LN1 -> FF1/FF2 (padded)
            _Float16 us[NB][260];              // 8320    FF1 -> FF2 (padded)
            float    ys[NB][128];              // 8192    FF2 -> LN2
        } ff;
    } u;
    float hs[NB][128];                         // 8192    residual
    union {
        float attn[NB][16][8];                 // 8192    P2 -> P4
        float yln[NB][128];                    // 8192    G1 -> LN1
    } v;
    int   nls[NB][16];                         // 1024
    int   adjs[NB][16];                        // 1024
    float ssrc[NB][8];                         // 512
};

template <bool F32>
static __device__ __forceinline__ void gat_body(
        Smem& s,
        const void* __restrict__ h,
        const int*  __restrict__ adj,
        const int*  __restrict__ n_list,
        const _Float16* __restrict__ ssrc_h,
        const _Float16* __restrict__ sdst_h,
        const _Float16* __restrict__ WeffT,
        const void* __restrict__ g1, const void* __restrict__ bb1,
        const void* __restrict__ w1, const void* __restrict__ fb1,
        const void* __restrict__ w2, const void* __restrict__ fb2,
        const void* __restrict__ g2, const void* __restrict__ bb2,
        void* __restrict__ out) {
    using P = Pol<F32>;
    const int t   = threadIdx.x;
    const int bn0 = blockIdx.x * NB;
    const int b   = bn0 >> 9;                  // 512 nodes per batch
    const int l   = t & 63;
    const int w   = t >> 6;                    // wave 0..7
    const int lo  = l & 15;
    const int hi  = l >> 4;

    // ---- P1: self rows + neighbor lists + gathered ssrc  (512 threads)
    {
        const int r = t >> 5, c0 = (t & 31) * 4;
        const float4 v = P::ld4(h, (bn0 + r) * 128 + c0);
        *(float4*)&s.hs[r][c0] = v;
    }
    if (t < 256) {
        const int r = t >> 4, m = t & 15;
        s.nls[r][m]  = n_list[(bn0 + r) * M_ + m] & (N_ - 1);
        s.adjs[r][m] = adj[(bn0 + r) * M_ + m];
    }
    if (t < NB * 8) s.ssrc[t >> 3][t & 7] = (float)ssrc_h[bn0 * 8 + t];
    __syncthreads();

    // ---- P2: scores = mask(leaky(s_src + s_dst[nl]))   (256 threads)
    if (t < 256) {
        const int r = t >> 4, m = t & 15;
        const int nbr = s.nls[r][m];
        const f16x8 sd = *(const f16x8*)(sdst_h + (size_t)(b * N_ + nbr) * 8);
        const int amask = s.adjs[r][m];
        float sc[8];
        #pragma unroll
        for (int hh = 0; hh < 8; ++hh) {
            float x = s.ssrc[r][hh] + (float)sd[hh];
            x = x > 0.f ? x : 0.2f * x;        // leaky_relu BEFORE mask (ref order)
            if (amask == 0) x = -1e9f;
            sc[hh] = x;
        }
        *(float4*)&s.v.attn[r][m][0] = make_float4(sc[0], sc[1], sc[2], sc[3]);
        *(float4*)&s.v.attn[r][m][4] = make_float4(sc[4], sc[5], sc[6], sc[7]);
    }
    __syncthreads();

    // ---- P3: softmax over m   (128 threads)
    if (t < NB * 8) {
        const int r = t >> 3, hh = t & 7;
        float mx = -3.4e38f;
        #pragma unroll
        for (int m = 0; m < 16; ++m) mx = fmaxf(mx, s.v.attn[r][m][hh]);
        float ex[16], sum = 0.f;
        #pragma unroll
        for (int m = 0; m < 16; ++m) { ex[m] = __expf(s.v.attn[r][m][hh] - mx); sum += ex[m]; }
        const float inv = 1.f / sum;
        #pragma unroll
        for (int m = 0; m < 16; ++m) s.v.attn[r][m][hh] = ex[m] * inv;
    }
    __syncthreads();

    // ---- P4: Z[r][hh][d] = sum_m attn[r][m][hh] * h[nl[r][m]][d]
    //      512 threads: 32 threads/node, 4 d each.  (f16, swizzled)
    {
        const int r = t >> 5, dc = t & 31, d0 = dc * 4;
        float z[8][4];
        #pragma unroll
        for (int hh = 0; hh < 8; ++hh)
            #pragma unroll
            for (int jj = 0; jj < 4; ++jj) z[hh][jj] = 0.f;
        #pragma unroll 4
        for (int m = 0; m < 16; ++m) {
            const int nbr = s.nls[r][m];
            const float4 hv = P::ld4(h, (b * N_ + nbr) * 128 + d0);
            const float hv4[4] = { hv.x, hv.y, hv.z, hv.w };
            const float4 a0 = *(const float4*)&s.v.attn[r][m][0];
            const float4 a1 = *(const float4*)&s.v.attn[r][m][4];
            const float av[8] = { a0.x, a0.y, a0.z, a0.w, a1.x, a1.y, a1.z, a1.w };
            #pragma unroll
            for (int hh = 0; hh < 8; ++hh)
                #pragma unroll
                for (int jj = 0; jj < 4; ++jj) z[hh][jj] += av[hh] * hv4[jj];
        }
        char* zb = (char*)&s.u.Zh[0][0] + r * 2048;
        const int xo = (r & 7) << 4;
        #pragma unroll
        for (int hh = 0; hh < 8; ++hh) {
            f16x4 vv;
            #pragma unroll
            for (int jj = 0; jj < 4; ++jj) vv[jj] = (_Float16)z[hh][jj];
            *(f16x4*)(zb + ((hh * 256 + dc * 8) ^ xo)) = vv;
        }
    }
    __syncthreads();

    // ---- G1: yln = Zh @ WeffT^T + hs   (MFMA 16x16x16, K=1024; 8 waves x 16 cols)
    {
        const char* za  = (const char*)&s.u.Zh[0][0] + lo * 2048;
        const int   xo  = (lo & 7) << 4;
        const char* wb0 = (const char*)(WeffT + (size_t)(w * 16 + lo) * 1024);
        f32x4 acc0 = {0.f, 0.f, 0.f, 0.f};
        #pragma unroll 8
        for (int ks = 0; ks < 64; ++ks) {
            const int kb = ks * 32 + hi * 8;           // byte offset of k = ks*16 + hi*4
            const f16x4 a  = *(const f16x4*)(za + (kb ^ xo));
            const f16x4 b0 = *(const f16x4*)(wb0 + kb);
            acc0 = __builtin_amdgcn_mfma_f32_16x16x16f16(a, b0, acc0, 0, 0, 0);
        }
        const int o0 = w * 16 + lo;
        #pragma unroll
        for (int q = 0; q < 4; ++q) {
            const int rr = hi * 4 + q;
            s.v.yln[rr][o0] = acc0[q] + s.hs[rr][o0];
        }
    }
    __syncthreads();

    // ---- LN1 -> ts (f32, padded rows). 16 threads per row (256 threads).
    if (t < 256) {
        const int r = t >> 4, j0 = (t & 15) * 8;
        const float4 x0 = *(const float4*)&s.v.yln[r][j0];
        const float4 x1 = *(const float4*)&s.v.yln[r][j0 + 4];
        const float x[8] = { x0.x, x0.y, x0.z, x0.w, x1.x, x1.y, x1.z, x1.w };
        float sm = 0.f, ss = 0.f;
        #pragma unroll
        for (int j = 0; j < 8; ++j) { sm += x[j]; ss += x[j] * x[j]; }
        #pragma unroll
        for (int off = 8; off > 0; off >>= 1) {
            sm += __shfl_xor(sm, off);
            ss += __shfl_xor(ss, off);
        }
        const float mu   = sm * (1.f / 128.f);
        const float var  = ss * (1.f / 128.f) - mu * mu;
        const float rstd = rsqrtf(var + 1e-5f);
        float gv[8], bv[8];
        P::ld8(g1, j0, gv);
        P::ld8(bb1, j0, bv);
        #pragma unroll
        for (int j = 0; j < 8; ++j)
            s.u.ff.ts[r][j0 + j] = (x[j] - mu) * rstd * gv[j] + bv[j];
    }
    __syncthreads();

    // ---- FF1: us = relu(ts @ w1 + b1)  (MFMA; 8 waves x 32 cols; K=128)
    {
        f32x4 acc[2] = { {0.f,0.f,0.f,0.f}, {0.f,0.f,0.f,0.f} };
        #pragma unroll
        for (int ks = 0; ks < 8; ++ks) {
            const int k = ks * 16 + hi * 4;
            const float4 tv = *(const float4*)&s.u.ff.ts[lo][k];
            f16x4 a;
            a[0] = (_Float16)tv.x; a[1] = (_Float16)tv.y;
            a[2] = (_Float16)tv.z; a[3] = (_Float16)tv.w;
            #pragma unroll
            for (int nt = 0; nt < 2; ++nt) {
                const int o = w * 32 + nt * 16 + lo;
                f16x4 bb;
                #pragma unroll
                for (int j = 0; j < 4; ++j) bb[j] = (_Float16)P::ld(w1, (k + j) * 256 + o);
                acc[nt] = __builtin_amdgcn_mfma_f32_16x16x16f16(a, bb, acc[nt], 0, 0, 0);
            }
        }
        #pragma unroll
        for (int nt = 0; nt < 2; ++nt) {
            const int o = w * 32 + nt * 16 + lo;
            const float bias = P::ld(fb1, o);
            #pragma unroll
            for (int q = 0; q < 4; ++q)
                s.u.ff.us[hi * 4 + q][o] = (_Float16)fmaxf(acc[nt][q] + bias, 0.f);
        }
    }
    __syncthreads();

    // ---- FF2: ys = us @ w2 + b2 + ts  (MFMA; 8 waves x 16 cols; K=256)
    {
        const int o0 = w * 16 + lo;
        f32x4 acc = {0.f, 0.f, 0.f, 0.f};
        #pragma unroll
        for (int ks = 0; ks < 16; ++ks) {
            const int k = ks * 16 + hi * 4;
            const f16x4 a = *(const f16x4*)&s.u.ff.us[lo][k];
            f16x4 bb;
            #pragma unroll
            for (int j = 0; j < 4; ++j) bb[j] = (_Float16)P::ld(w2, (k + j) * 128 + o0);
            acc = __builtin_amdgcn_mfma_f32_16x16x16f16(a, bb, acc, 0, 0, 0);
        }
        const float bias = P::ld(fb2, o0);
        #pragma unroll
        for (int q = 0; q < 4; ++q) {
            const int rr = hi * 4 + q;
            s.u.ff.ys[rr][o0] = acc[q] + bias + s.u.ff.ts[rr][o0];
        }
    }
    __syncthreads();

    // ---- LN2 -> out. 16 threads per row (256 threads).
    if (t < 256) {
        const int r = t >> 4, j0 = (t & 15) * 8;
        const float4 x0 = *(const float4*)&s.u.ff.ys[r][j0];
        const float4 x1 = *(const float4*)&s.u.ff.ys[r][j0 + 4];
        const float x[8] = { x0.x, x0.y, x0.z, x0.w, x1.x, x1.y, x1.z, x1.w };
        float sm = 0.f, ss = 0.f;
        #pragma unroll
        for (int j = 0; j < 8; ++j) { sm += x[j]; ss += x[j] * x[j]; }
        #pragma unroll
        for (int off = 8; off > 0; off >>= 1) {
            sm += __shfl_xor(sm, off);
            ss += __shfl_xor(ss, off);
        }
        const float mu   = sm * (1.f / 128.f);
        const float var  = ss * (1.f / 128.f) - mu * mu;
        const float rstd = rsqrtf(var + 1e-5f);
        float gv[8], bv[8], o8[8];
        P::ld8(g2, j0, gv);
        P::ld8(bb2, j0, bv);
        #pragma unroll
        for (int j = 0; j < 8; ++j) o8[j] = (x[j] - mu) * rstd * gv[j] + bv[j];
        P::st8(out, (long)(bn0 + r) * 128 + j0, o8);
    }
}

__global__ __launch_bounds__(512) void k_gat(
        const void* __restrict__ h,
        const int*  __restrict__ adj,
        const int*  __restrict__ n_list,
        const _Float16* __restrict__ ssrc_h,
        const _Float16* __restrict__ sdst_h,
        const _Float16* __restrict__ WeffT,
        const void* __restrict__ g1, const void* __restrict__ bb1,
        const void* __restrict__ w1, const void* __restrict__ fb1,
        const void* __restrict__ w2, const void* __restrict__ fb2,
        const void* __restrict__ g2, const void* __restrict__ bb2,
        void* __restrict__ out) {
    __shared__ Smem s;
    if (probe_is_f32(h))
        gat_body<true >(s, h, adj, n_list, ssrc_h, sdst_h, WeffT,
                        g1, bb1, w1, fb1, w2, fb2, g2, bb2, out);
    else
        gat_body<false>(s, h, adj, n_list, ssrc_h, sdst_h, WeffT,
                        g1, bb1, w1, fb1, w2, fb2, g2, bb2, out);
}

// ---------------------------------------------------------------------------
extern "C" void kernel_launch(void* const* d_in, const int* in_sizes, int n_in,
                              void* d_out, int out_size, void* d_ws, size_t ws_size,
                              hipStream_t stream) {
    (void)in_sizes; (void)n_in; (void)out_size; (void)ws_size;

    // ws layout (bytes) — total 532480, identical footprint to the proven kernel:
    //   wsrc   [     0,   4096)  f32[1024]
    //   wdst   [  4096,   8192)  f32[1024]
    //   ssrc   [  8192, 139264)  f16[8192*8]
    //   sdst   [139264, 270336)  f16[8192*8]
    //   WeffT  [270336, 532480)  f16[128][1024]
    char* wsb = (char*)d_ws;
    float*     wsrc  = (float*)(wsb);
    float*     wdst  = (float*)(wsb + 4096);
    _Float16*  ssrc  = (_Float16*)(wsb + 8192);
    _Float16*  sdst  = (_Float16*)(wsb + 139264);
    _Float16*  WeffT = (_Float16*)(wsb + 270336);

    k0<<<520,      256, 0, stream>>>(d_in[3], d_in[6], d_in[4], d_in[5], d_in[0],
                                     wsrc, wdst, WeffT);
    k1<<<BN_ / 16, 256, 0, stream>>>(d_in[0], wsrc, wdst, ssrc, sdst);
    k_gat<<<BN_ / NB, 512, 0, stream>>>(
        d_in[0], (const int*)d_in[1], (const int*)d_in[2], ssrc, sdst, WeffT,
        d_in[7], d_in[8], d_in[9], d_in[10], d_in[11], d_in[12],
        d_in[13], d_in[14], d_out);
}